// Round 1
// baseline (1196.697 us; speedup 1.0000x reference)
//
#include <hip/hip_runtime.h>
#include <stdint.h>

// ---------------- marching-tets tables ----------------
static __device__ __constant__ int d_TRI[16][6] = {
  {-1,-1,-1,-1,-1,-1},{1,0,2,-1,-1,-1},{4,0,3,-1,-1,-1},{1,4,2,1,3,4},
  {3,1,5,-1,-1,-1},{2,3,0,2,5,3},{1,4,0,1,5,4},{4,2,5,-1,-1,-1},
  {4,5,2,-1,-1,-1},{4,1,0,4,5,1},{3,2,0,3,5,2},{1,3,5,-1,-1,-1},
  {4,1,2,4,3,1},{3,0,4,-1,-1,-1},{2,0,1,-1,-1,-1},{-1,-1,-1,-1,-1,-1}};
static __device__ __constant__ int d_NT[16] = {0,1,1,2,1,2,2,1,1,2,2,1,2,1,1,0};
static __device__ __constant__ int d_EA[6] = {0,0,0,1,1,2};
static __device__ __constant__ int d_EB[6] = {1,2,3,2,3,3};

// ---------------- scan (exclusive, u32, out has n+1 entries) ----------------
#define SB 256
#define SI 8
#define STILE (SB*SI)

__global__ void k_scan_partial(const unsigned* __restrict__ in, unsigned* __restrict__ bsum, int n) {
  int b = blockIdx.x;
  int base = b * STILE;
  __shared__ unsigned sh[SB];
  unsigned s = 0;
  for (int i = threadIdx.x; i < STILE; i += SB) {
    int idx = base + i;
    s += (idx < n) ? in[idx] : 0u;
  }
  sh[threadIdx.x] = s; __syncthreads();
  for (int st = SB/2; st > 0; st >>= 1) {
    if (threadIdx.x < st) sh[threadIdx.x] += sh[threadIdx.x + st];
    __syncthreads();
  }
  if (threadIdx.x == 0) bsum[b] = sh[0];
}

// single block; B <= STILE required (max here: 1.5M/2048 = 733)
__global__ void k_scan_mid(const unsigned* __restrict__ bsum, unsigned* __restrict__ boff,
                           int B, unsigned* __restrict__ total_dst) {
  int t = threadIdx.x;
  unsigned loc[SI];
  int base = t * SI;
  unsigned s = 0;
  #pragma unroll
  for (int i = 0; i < SI; ++i) {
    int idx = base + i;
    unsigned v = (idx < B) ? bsum[idx] : 0u;
    loc[i] = s; s += v;
  }
  __shared__ unsigned sh[SB];
  sh[t] = s; __syncthreads();
  for (int o = 1; o < SB; o <<= 1) {
    unsigned v = (t >= o) ? sh[t - o] : 0u;
    __syncthreads();
    sh[t] += v;
    __syncthreads();
  }
  unsigned texcl = sh[t] - s;
  #pragma unroll
  for (int i = 0; i < SI; ++i) {
    int idx = base + i;
    if (idx < B) boff[idx] = texcl + loc[i];
  }
  if (t == SB - 1 && total_dst) *total_dst = sh[SB - 1];
}

__global__ void k_scan_final(const unsigned* __restrict__ in, const unsigned* __restrict__ boff,
                             unsigned* __restrict__ out, int n) {
  int b = blockIdx.x;
  int base = b * STILE + threadIdx.x * SI;
  unsigned loc[SI];
  unsigned s = 0;
  #pragma unroll
  for (int i = 0; i < SI; ++i) {
    int idx = base + i;
    unsigned v = (idx < n) ? in[idx] : 0u;
    loc[i] = s; s += v;
  }
  __shared__ unsigned sh[SB];
  int t = threadIdx.x;
  sh[t] = s; __syncthreads();
  for (int o = 1; o < SB; o <<= 1) {
    unsigned v = (t >= o) ? sh[t - o] : 0u;
    __syncthreads();
    sh[t] += v;
    __syncthreads();
  }
  unsigned texcl = sh[t] - s;
  unsigned bo = boff[b];
  #pragma unroll
  for (int i = 0; i < SI; ++i) {
    int idx = base + i;
    if (idx < n) out[idx] = bo + texcl + loc[i];
  }
}

// ---------------- pipeline kernels ----------------
__global__ void k_copy_u32(unsigned* __restrict__ dst, const unsigned* __restrict__ src, int n) {
  int i = blockIdx.x * blockDim.x + threadIdx.x;
  if (i < n) dst[i] = src[i];
}

// per-tet: classification + per-lo-bucket crossing-edge histogram + tri-count flags
__global__ void k_classify(const int* __restrict__ tet, const float* __restrict__ sdf,
                           unsigned* __restrict__ cnt, unsigned* __restrict__ t1,
                           unsigned* __restrict__ t2, int F) {
  int f = blockIdx.x * blockDim.x + threadIdx.x;
  if (f >= F) return;
  int4 q = reinterpret_cast<const int4*>(tet)[f];
  int v[4] = {q.x, q.y, q.z, q.w};
  int oc[4];
  #pragma unroll
  for (int i = 0; i < 4; ++i) oc[i] = sdf[v[i]] > 0.0f;
  int s = oc[0] + oc[1] + oc[2] + oc[3];
  int valid = (s > 0) & (s < 4);
  int tix = oc[0] | (oc[1] << 1) | (oc[2] << 2) | (oc[3] << 3);
  int nt = valid ? d_NT[tix] : 0;
  t1[f] = (nt == 1) ? 1u : 0u;
  t2[f] = (nt == 2) ? 1u : 0u;
  if (!valid) return;
  #pragma unroll
  for (int e = 0; e < 6; ++e) {
    int a = v[d_EA[e]], b = v[d_EB[e]];
    if (oc[d_EA[e]] != oc[d_EB[e]]) {
      int lo = a < b ? a : b;
      atomicAdd(&cnt[lo], 1u);
    }
  }
}

__global__ void k_scatter(const int* __restrict__ tet, const float* __restrict__ sdf,
                          unsigned* __restrict__ cursor, unsigned* __restrict__ inst, int F) {
  int f = blockIdx.x * blockDim.x + threadIdx.x;
  if (f >= F) return;
  int4 q = reinterpret_cast<const int4*>(tet)[f];
  int v[4] = {q.x, q.y, q.z, q.w};
  int oc[4];
  #pragma unroll
  for (int i = 0; i < 4; ++i) oc[i] = sdf[v[i]] > 0.0f;
  int s = oc[0] + oc[1] + oc[2] + oc[3];
  if (s == 0 || s == 4) return;
  #pragma unroll
  for (int e = 0; e < 6; ++e) {
    int a = v[d_EA[e]], b = v[d_EB[e]];
    if (oc[d_EA[e]] != oc[d_EB[e]]) {
      int lo = a < b ? a : b;
      int hi = a < b ? b : a;
      unsigned p = atomicAdd(&cursor[lo], 1u);
      inst[p] = (unsigned)hi;
    }
  }
}

// one 64-thread block per lo-bucket: rank-sort hi values, dedupe in place.
// sorted output temporarily staged in uniqtmp[base..]; unique prefix written back to inst[base..].
#define SORT_CAP 2048
__global__ void k_sortdedupe(const unsigned* __restrict__ off, unsigned* __restrict__ inst,
                             unsigned* __restrict__ uniqtmp, unsigned* __restrict__ ucnt, int N) {
  int v0 = blockIdx.x;
  if (v0 >= N) return;
  unsigned base = off[v0];
  unsigned n = off[v0 + 1] - base;
  if (n == 0) { if (threadIdx.x == 0) ucnt[v0] = 0u; return; }
  __shared__ unsigned sv[SORT_CAP];
  if (n <= SORT_CAP) {
    for (unsigned k = threadIdx.x; k < n; k += 64) sv[k] = inst[base + k];
    __syncthreads();
    for (unsigned k = threadIdx.x; k < n; k += 64) {
      unsigned val = sv[k];
      unsigned r = 0;
      for (unsigned j = 0; j < n; ++j) {
        unsigned w = sv[j];
        r += (w < val) || (w == val && j < k);
      }
      uniqtmp[base + r] = val;
    }
  } else {
    // fallback (practically unreachable at this scale)
    for (unsigned k = threadIdx.x; k < n; k += 64) {
      unsigned val = inst[base + k];
      unsigned r = 0;
      for (unsigned j = 0; j < n; ++j) {
        unsigned w = inst[base + j];
        r += (w < val) || (w == val && j < k);
      }
      uniqtmp[base + r] = val;
    }
  }
  __syncthreads();
  if (threadIdx.x == 0) {
    unsigned u = 0, prev = 0xFFFFFFFFu;
    for (unsigned k = 0; k < n; ++k) {
      unsigned val = uniqtmp[base + k];
      if (k == 0 || val != prev) { inst[base + u++] = val; prev = val; }
    }
    ucnt[v0] = u;
  }
}

// compact unique edges to uniq[uoff[lo]+k] and emit interpolated verts in rank order
__global__ void k_verts(const unsigned* __restrict__ off, const unsigned* __restrict__ uoff,
                        const unsigned* __restrict__ ucnt, const unsigned* __restrict__ inst,
                        unsigned* __restrict__ uniq, const float* __restrict__ pos,
                        const float* __restrict__ sdf, float* __restrict__ out, int N) {
  int v0 = blockIdx.x;
  if (v0 >= N) return;
  unsigned u = ucnt[v0];
  if (u == 0) return;
  unsigned base = off[v0], ub = uoff[v0];
  float a = sdf[v0];
  float p0x = pos[3 * (size_t)v0 + 0], p0y = pos[3 * (size_t)v0 + 1], p0z = pos[3 * (size_t)v0 + 2];
  for (unsigned k = threadIdx.x; k < u; k += 64) {
    unsigned v1 = inst[base + k];
    unsigned r = ub + k;
    uniq[r] = v1;
    float b = sdf[v1];
    float d = a - b;
    float w0 = -b / d;
    float w1 = a / d;
    size_t ro = (size_t)3 * r;
    out[ro + 0] = p0x * w0 + pos[3 * (size_t)v1 + 0] * w1;
    out[ro + 1] = p0y * w0 + pos[3 * (size_t)v1 + 1] * w1;
    out[ro + 2] = p0z * w0 + pos[3 * (size_t)v1 + 2] * w1;
  }
}

// per-tet face emission: faces1 block (nt==1 tets, tet order) then faces2 block (nt==2)
__global__ void k_faces(const int* __restrict__ tet, const float* __restrict__ sdf,
                        const unsigned* __restrict__ uoff, const unsigned* __restrict__ ucnt,
                        const unsigned* __restrict__ uniq, const unsigned* __restrict__ P1,
                        const unsigned* __restrict__ P2, float* __restrict__ out, int F, int N) {
  int f = blockIdx.x * blockDim.x + threadIdx.x;
  if (f >= F) return;
  int4 q = reinterpret_cast<const int4*>(tet)[f];
  int v[4] = {q.x, q.y, q.z, q.w};
  int oc[4];
  #pragma unroll
  for (int i = 0; i < 4; ++i) oc[i] = sdf[v[i]] > 0.0f;
  int s = oc[0] + oc[1] + oc[2] + oc[3];
  if (s == 0 || s == 4) return;
  int tix = oc[0] | (oc[1] << 1) | (oc[2] << 2) | (oc[3] << 3);
  int nt = d_NT[tix];
  int rank[6];
  #pragma unroll
  for (int e = 0; e < 6; ++e) {
    int a = v[d_EA[e]], b = v[d_EB[e]];
    if (oc[d_EA[e]] != oc[d_EB[e]]) {
      int lo = a < b ? a : b;
      int hi = a < b ? b : a;
      unsigned lbase = uoff[lo];
      unsigned len = ucnt[lo];
      unsigned loI = 0, hiI = len;
      while (loI < hiI) {
        unsigned mid = (loI + hiI) >> 1;
        if ((int)uniq[lbase + mid] < hi) loI = mid + 1; else hiI = mid;
      }
      rank[e] = (int)(lbase + loI);
    } else {
      rank[e] = -1;
    }
  }
  unsigned M = uoff[N];
  float* fo = out + (size_t)3 * M;
  const int* tt = d_TRI[tix];
  if (nt == 1) {
    unsigned r = P1[f];
    size_t o = (size_t)3 * r;
    fo[o + 0] = (float)rank[tt[0]];
    fo[o + 1] = (float)rank[tt[1]];
    fo[o + 2] = (float)rank[tt[2]];
  } else {
    unsigned T1 = P1[F];
    unsigned r0 = T1 + 2u * P2[f];
    size_t o = (size_t)3 * r0;
    #pragma unroll
    for (int c = 0; c < 6; ++c) fo[o + c] = (float)rank[tt[c]];
  }
}

// ---------------- host launcher ----------------
static void run_scan(const unsigned* in, unsigned* out, int n,
                     unsigned* bsum, unsigned* boff, hipStream_t s) {
  int B = (n + STILE - 1) / STILE;
  k_scan_partial<<<B, SB, 0, s>>>(in, bsum, n);
  k_scan_mid<<<1, SB, 0, s>>>(bsum, boff, B, out + n);
  k_scan_final<<<B, SB, 0, s>>>(in, boff, out, n);
}

extern "C" void kernel_launch(void* const* d_in, const int* in_sizes, int n_in,
                              void* d_out, int out_size, void* d_ws, size_t ws_size,
                              hipStream_t stream) {
  const float* pos = (const float*)d_in[0];
  const float* sdf = (const float*)d_in[1];
  const int* tet = (const int*)d_in[2];
  int N = in_sizes[1];
  int F = in_sizes[2] / 4;
  float* out = (float*)d_out;

  char* w = (char*)d_ws;
  size_t o = 0;
  auto take = [&](size_t bytes) -> char* {
    char* p = w + o;
    o = (o + bytes + 255) & ~(size_t)255;
    return p;
  };
  unsigned* cnt    = (unsigned*)take((size_t)(N + 1) * 4);
  unsigned* off    = (unsigned*)take((size_t)(N + 1) * 4);
  unsigned* cursor = (unsigned*)take((size_t)(N + 1) * 4);
  unsigned* ucnt   = (unsigned*)take((size_t)(N + 1) * 4);
  unsigned* uoff   = (unsigned*)take((size_t)(N + 1) * 4);
  unsigned* t1     = (unsigned*)take((size_t)(F + 1) * 4);
  unsigned* P1     = (unsigned*)take((size_t)(F + 1) * 4);
  unsigned* t2     = (unsigned*)take((size_t)(F + 1) * 4);
  unsigned* P2     = (unsigned*)take((size_t)(F + 1) * 4);
  unsigned* inst   = (unsigned*)take((size_t)4 * F * 4);
  unsigned* uniq   = (unsigned*)take((size_t)4 * F * 4);
  unsigned* bsum   = (unsigned*)take(4096 * 4);
  unsigned* boff   = (unsigned*)take(4096 * 4);

  int TB = 256;
  int FB = (F + TB - 1) / TB;

  // 1) zero the per-lo histogram
  hipMemsetAsync(cnt, 0, (size_t)N * 4, stream);
  // 2) classify + histogram + tri flags
  k_classify<<<FB, TB, 0, stream>>>(tet, sdf, cnt, t1, t2, F);
  // 3) bucket offsets
  run_scan(cnt, off, N, bsum, boff, stream);
  // 4) cursor = off
  k_copy_u32<<<(N + TB - 1) / TB, TB, 0, stream>>>(cursor, off, N);
  // 5) scatter hi values into buckets
  k_scatter<<<FB, TB, 0, stream>>>(tet, sdf, cursor, inst, F);
  // 6) per-bucket sort + dedupe
  k_sortdedupe<<<N, 64, 0, stream>>>(off, inst, uniq, ucnt, N);
  // 7) unique offsets (global lexicographic ranks); uoff[N] = M
  run_scan(ucnt, uoff, N, bsum, boff, stream);
  // 8) compact unique edges + emit verts
  k_verts<<<N, 64, 0, stream>>>(off, uoff, ucnt, inst, uniq, pos, sdf, out, N);
  // 9) face row offsets
  run_scan(t1, P1, F, bsum, boff, stream);
  run_scan(t2, P2, F, bsum, boff, stream);
  // 10) emit faces
  k_faces<<<FB, TB, 0, stream>>>(tet, sdf, uoff, ucnt, uniq, P1, P2, out, F, N);
}

// Round 2
// 970.687 us; speedup vs baseline: 1.2328x; 1.2328x over previous
//
#include <hip/hip_runtime.h>
#include <stdint.h>

// ---------------- marching-tets tables ----------------
static __device__ __constant__ int d_TRI[16][6] = {
  {-1,-1,-1,-1,-1,-1},{1,0,2,-1,-1,-1},{4,0,3,-1,-1,-1},{1,4,2,1,3,4},
  {3,1,5,-1,-1,-1},{2,3,0,2,5,3},{1,4,0,1,5,4},{4,2,5,-1,-1,-1},
  {4,5,2,-1,-1,-1},{4,1,0,4,5,1},{3,2,0,3,5,2},{1,3,5,-1,-1,-1},
  {4,1,2,4,3,1},{3,0,4,-1,-1,-1},{2,0,1,-1,-1,-1},{-1,-1,-1,-1,-1,-1}};
static __device__ __constant__ int d_NT[16] = {0,1,1,2,1,2,2,1,1,2,2,1,2,1,1,0};
static __device__ __constant__ int d_EA[6] = {0,0,0,1,1,2};
static __device__ __constant__ int d_EB[6] = {1,2,3,2,3,3};

__device__ __forceinline__ void wave_sync_lds() {
  __builtin_amdgcn_sched_barrier(0);
  asm volatile("s_waitcnt lgkmcnt(0)" ::: "memory");
  __builtin_amdgcn_sched_barrier(0);
}
__device__ __forceinline__ void wave_sync_vm() {
  __builtin_amdgcn_sched_barrier(0);
  asm volatile("s_waitcnt vmcnt(0)" ::: "memory");
  __builtin_amdgcn_sched_barrier(0);
}

// ---------------- scan (exclusive, u32, out has n+1 entries) ----------------
#define SB 256
#define SI 8
#define STILE (SB*SI)

__global__ void k_scan_partial(const unsigned* __restrict__ in, unsigned* __restrict__ bsum, int n) {
  int b = blockIdx.x;
  int base = b * STILE;
  __shared__ unsigned sh[SB];
  unsigned s = 0;
  for (int i = threadIdx.x; i < STILE; i += SB) {
    int idx = base + i;
    s += (idx < n) ? in[idx] : 0u;
  }
  sh[threadIdx.x] = s; __syncthreads();
  for (int st = SB/2; st > 0; st >>= 1) {
    if (threadIdx.x < st) sh[threadIdx.x] += sh[threadIdx.x + st];
    __syncthreads();
  }
  if (threadIdx.x == 0) bsum[b] = sh[0];
}

// single block; B <= STILE required (max here: 3M/2048 = 1465)
__global__ void k_scan_mid(const unsigned* __restrict__ bsum, unsigned* __restrict__ boff,
                           int B, unsigned* __restrict__ total_dst) {
  int t = threadIdx.x;
  unsigned loc[SI];
  int base = t * SI;
  unsigned s = 0;
  #pragma unroll
  for (int i = 0; i < SI; ++i) {
    int idx = base + i;
    unsigned v = (idx < B) ? bsum[idx] : 0u;
    loc[i] = s; s += v;
  }
  __shared__ unsigned sh[SB];
  sh[t] = s; __syncthreads();
  for (int o = 1; o < SB; o <<= 1) {
    unsigned v = (t >= o) ? sh[t - o] : 0u;
    __syncthreads();
    sh[t] += v;
    __syncthreads();
  }
  unsigned texcl = sh[t] - s;
  #pragma unroll
  for (int i = 0; i < SI; ++i) {
    int idx = base + i;
    if (idx < B) boff[idx] = texcl + loc[i];
  }
  if (t == SB - 1 && total_dst) *total_dst = sh[SB - 1];
}

__global__ void k_scan_final(const unsigned* __restrict__ in, const unsigned* __restrict__ boff,
                             unsigned* __restrict__ out, int n) {
  int b = blockIdx.x;
  int base = b * STILE + threadIdx.x * SI;
  unsigned loc[SI];
  unsigned s = 0;
  #pragma unroll
  for (int i = 0; i < SI; ++i) {
    int idx = base + i;
    unsigned v = (idx < n) ? in[idx] : 0u;
    loc[i] = s; s += v;
  }
  __shared__ unsigned sh[SB];
  int t = threadIdx.x;
  sh[t] = s; __syncthreads();
  for (int o = 1; o < SB; o <<= 1) {
    unsigned v = (t >= o) ? sh[t - o] : 0u;
    __syncthreads();
    sh[t] += v;
    __syncthreads();
  }
  unsigned texcl = sh[t] - s;
  unsigned bo = boff[b];
  #pragma unroll
  for (int i = 0; i < SI; ++i) {
    int idx = base + i;
    if (idx < n) out[idx] = bo + texcl + loc[i];
  }
}

// ---------------- pipeline kernels ----------------

// per-tet: classification + per-lo-bucket crossing-edge histogram + tri-count flags
// t12[f] = 1-tri flag, t12[F+f] = 2-tri flag  (combined for a single fused scan)
__global__ void k_classify(const int* __restrict__ tet, const float* __restrict__ sdf,
                           unsigned* __restrict__ cnt, unsigned* __restrict__ t12, int F) {
  int f = blockIdx.x * blockDim.x + threadIdx.x;
  if (f >= F) return;
  int4 q = reinterpret_cast<const int4*>(tet)[f];
  int v[4] = {q.x, q.y, q.z, q.w};
  int oc[4];
  #pragma unroll
  for (int i = 0; i < 4; ++i) oc[i] = sdf[v[i]] > 0.0f;
  int s = oc[0] + oc[1] + oc[2] + oc[3];
  int valid = (s > 0) & (s < 4);
  int tix = oc[0] | (oc[1] << 1) | (oc[2] << 2) | (oc[3] << 3);
  int nt = valid ? d_NT[tix] : 0;
  t12[f] = (nt == 1) ? 1u : 0u;
  t12[F + f] = (nt == 2) ? 1u : 0u;
  if (!valid) return;
  #pragma unroll
  for (int e = 0; e < 6; ++e) {
    int a = v[d_EA[e]], b = v[d_EB[e]];
    if (oc[d_EA[e]] != oc[d_EB[e]]) {
      int lo = a < b ? a : b;
      atomicAdd(&cnt[lo], 1u);
    }
  }
}

// scatter hi values into buckets. DESTRUCTIVE on off: after this kernel
// off[v] = off_orig[v] + cnt[v]; consumers recompute base = off[v]-cnt[v].
__global__ void k_scatter(const int* __restrict__ tet, const float* __restrict__ sdf,
                          unsigned* __restrict__ off, unsigned* __restrict__ inst, int F) {
  int f = blockIdx.x * blockDim.x + threadIdx.x;
  if (f >= F) return;
  int4 q = reinterpret_cast<const int4*>(tet)[f];
  int v[4] = {q.x, q.y, q.z, q.w};
  int oc[4];
  #pragma unroll
  for (int i = 0; i < 4; ++i) oc[i] = sdf[v[i]] > 0.0f;
  int s = oc[0] + oc[1] + oc[2] + oc[3];
  if (s == 0 || s == 4) return;
  #pragma unroll
  for (int e = 0; e < 6; ++e) {
    int a = v[d_EA[e]], b = v[d_EB[e]];
    if (oc[d_EA[e]] != oc[d_EB[e]]) {
      int lo = a < b ? a : b;
      int hi = a < b ? b : a;
      unsigned p = atomicAdd(&off[lo], 1u);
      inst[p] = (unsigned)hi;
    }
  }
}

// one WAVE per lo-bucket, 4 buckets per 256-thread block.
// sort staged in LDS; wave-parallel ballot dedupe; unique prefix -> inst[base..].
#define CAP 512
__global__ void k_sortdedupe(const unsigned* __restrict__ off, const unsigned* __restrict__ cnt,
                             unsigned* __restrict__ inst, unsigned* __restrict__ gtmp,
                             unsigned* __restrict__ ucnt, int N) {
  __shared__ unsigned sA[4][CAP];
  __shared__ unsigned sBv[4][CAP];
  int w = threadIdx.x >> 6;
  int lane = threadIdx.x & 63;
  int v0 = blockIdx.x * 4 + w;
  if (v0 >= N) return;
  unsigned n = cnt[v0];
  if (n == 0) { if (lane == 0) ucnt[v0] = 0u; return; }
  unsigned base = off[v0] - n;  // off was destructively bumped by k_scatter

  if (n <= CAP) {
    for (unsigned k = lane; k < n; k += 64) sA[w][k] = inst[base + k];
    wave_sync_lds();
    for (unsigned k = lane; k < n; k += 64) {
      unsigned val = sA[w][k];
      unsigned r = 0;
      for (unsigned j = 0; j < n; ++j) {
        unsigned x = sA[w][j];
        r += (x < val) || (x == val && j < k);
      }
      sBv[w][r] = val;
    }
    wave_sync_lds();
    unsigned ub = 0;
    for (unsigned c = 0; c < n; c += 64) {
      unsigned k = c + (unsigned)lane;
      bool act = k < n;
      unsigned val = act ? sBv[w][k] : 0u;
      bool flag = act && (k == 0 || val != sBv[w][k - 1]);
      unsigned long long m = __ballot((int)flag);
      if (flag) {
        unsigned pos = ub + (unsigned)__popcll(m & ((1ull << lane) - 1ull));
        inst[base + pos] = val;
      }
      ub += (unsigned)__popcll(m);
    }
    if (lane == 0) ucnt[v0] = ub;
  } else {
    // fallback (practically unreachable: bucket sizes ~Poisson(15))
    for (unsigned k = lane; k < n; k += 64) {
      unsigned val = inst[base + k];
      unsigned r = 0;
      for (unsigned j = 0; j < n; ++j) {
        unsigned x = inst[base + j];
        r += (x < val) || (x == val && j < k);
      }
      gtmp[base + r] = val;
    }
    wave_sync_vm();
    __threadfence_block();
    if (lane == 0) {
      unsigned u = 0, prev = 0xFFFFFFFFu;
      for (unsigned k = 0; k < n; ++k) {
        unsigned val = gtmp[base + k];
        if (k == 0 || val != prev) { inst[base + u++] = val; prev = val; }
      }
      ucnt[v0] = u;
    }
  }
}

// compact unique edges to uniq[uoff[lo]+k] and emit interpolated verts in rank order.
// one WAVE per bucket, 4 buckets per block.
__global__ void k_verts(const unsigned* __restrict__ off, const unsigned* __restrict__ cnt,
                        const unsigned* __restrict__ uoff, const unsigned* __restrict__ ucnt,
                        const unsigned* __restrict__ inst, unsigned* __restrict__ uniq,
                        const float* __restrict__ pos, const float* __restrict__ sdf,
                        float* __restrict__ out, int N) {
  int w = threadIdx.x >> 6;
  int lane = threadIdx.x & 63;
  int v0 = blockIdx.x * 4 + w;
  if (v0 >= N) return;
  unsigned u = ucnt[v0];
  if (u == 0) return;
  unsigned base = off[v0] - cnt[v0];
  unsigned ub = uoff[v0];
  float a = sdf[v0];
  float p0x = pos[3 * (size_t)v0 + 0], p0y = pos[3 * (size_t)v0 + 1], p0z = pos[3 * (size_t)v0 + 2];
  for (unsigned k = lane; k < u; k += 64) {
    unsigned v1 = inst[base + k];
    unsigned r = ub + k;
    uniq[r] = v1;
    float b = sdf[v1];
    float d = a - b;
    float w0 = -b / d;
    float w1 = a / d;
    size_t ro = (size_t)3 * r;
    out[ro + 0] = p0x * w0 + pos[3 * (size_t)v1 + 0] * w1;
    out[ro + 1] = p0y * w0 + pos[3 * (size_t)v1 + 1] * w1;
    out[ro + 2] = p0z * w0 + pos[3 * (size_t)v1 + 2] * w1;
  }
}

// per-tet face emission using combined prefix C over [t1 | t2]:
// P1[f]=C[f], T1=C[F], P2[f]=C[F+f]-T1. faces1 block then faces2 block.
__global__ void k_faces(const int* __restrict__ tet, const float* __restrict__ sdf,
                        const unsigned* __restrict__ uoff, const unsigned* __restrict__ ucnt,
                        const unsigned* __restrict__ uniq, const unsigned* __restrict__ C,
                        float* __restrict__ out, int F, int N) {
  int f = blockIdx.x * blockDim.x + threadIdx.x;
  if (f >= F) return;
  int4 q = reinterpret_cast<const int4*>(tet)[f];
  int v[4] = {q.x, q.y, q.z, q.w};
  int oc[4];
  #pragma unroll
  for (int i = 0; i < 4; ++i) oc[i] = sdf[v[i]] > 0.0f;
  int s = oc[0] + oc[1] + oc[2] + oc[3];
  if (s == 0 || s == 4) return;
  int tix = oc[0] | (oc[1] << 1) | (oc[2] << 2) | (oc[3] << 3);
  int nt = d_NT[tix];
  int rank[6];
  #pragma unroll
  for (int e = 0; e < 6; ++e) {
    int a = v[d_EA[e]], b = v[d_EB[e]];
    if (oc[d_EA[e]] != oc[d_EB[e]]) {
      int lo = a < b ? a : b;
      int hi = a < b ? b : a;
      unsigned lbase = uoff[lo];
      unsigned len = ucnt[lo];
      unsigned loI = 0, hiI = len;
      while (loI < hiI) {
        unsigned mid = (loI + hiI) >> 1;
        if ((int)uniq[lbase + mid] < hi) loI = mid + 1; else hiI = mid;
      }
      rank[e] = (int)(lbase + loI);
    } else {
      rank[e] = -1;
    }
  }
  unsigned M = uoff[N];
  float* fo = out + (size_t)3 * M;
  const int* tt = d_TRI[tix];
  if (nt == 1) {
    unsigned r = C[f];
    size_t o = (size_t)3 * r;
    fo[o + 0] = (float)rank[tt[0]];
    fo[o + 1] = (float)rank[tt[1]];
    fo[o + 2] = (float)rank[tt[2]];
  } else {
    unsigned T1 = C[F];
    unsigned r0 = T1 + 2u * (C[F + f] - T1);
    size_t o = (size_t)3 * r0;
    #pragma unroll
    for (int c = 0; c < 6; ++c) fo[o + c] = (float)rank[tt[c]];
  }
}

// ---------------- host launcher ----------------
static void run_scan(const unsigned* in, unsigned* out, int n,
                     unsigned* bsum, unsigned* boff, hipStream_t s) {
  int B = (n + STILE - 1) / STILE;
  k_scan_partial<<<B, SB, 0, s>>>(in, bsum, n);
  k_scan_mid<<<1, SB, 0, s>>>(bsum, boff, B, out + n);
  k_scan_final<<<B, SB, 0, s>>>(in, boff, out, n);
}

extern "C" void kernel_launch(void* const* d_in, const int* in_sizes, int n_in,
                              void* d_out, int out_size, void* d_ws, size_t ws_size,
                              hipStream_t stream) {
  const float* pos = (const float*)d_in[0];
  const float* sdf = (const float*)d_in[1];
  const int* tet = (const int*)d_in[2];
  int N = in_sizes[1];
  int F = in_sizes[2] / 4;
  float* out = (float*)d_out;

  char* w = (char*)d_ws;
  size_t o = 0;
  auto take = [&](size_t bytes) -> char* {
    char* p = w + o;
    o = (o + bytes + 255) & ~(size_t)255;
    return p;
  };
  unsigned* cnt  = (unsigned*)take((size_t)(N + 1) * 4);
  unsigned* off  = (unsigned*)take((size_t)(N + 1) * 4);
  unsigned* ucnt = (unsigned*)take((size_t)(N + 1) * 4);
  unsigned* uoff = (unsigned*)take((size_t)(N + 1) * 4);
  unsigned* t12  = (unsigned*)take((size_t)2 * F * 4);
  unsigned* C    = (unsigned*)take(((size_t)2 * F + 1) * 4);
  unsigned* inst = (unsigned*)take((size_t)4 * F * 4);
  unsigned* uniq = (unsigned*)take((size_t)4 * F * 4);
  unsigned* bsum = (unsigned*)take(4096 * 4);
  unsigned* boff = (unsigned*)take(4096 * 4);

  int TB = 256;
  int FB = (F + TB - 1) / TB;
  int NB4 = (N + 3) / 4;

  // 1) zero the per-lo histogram
  hipMemsetAsync(cnt, 0, (size_t)N * 4, stream);
  // 2) classify + histogram + combined tri flags
  k_classify<<<FB, TB, 0, stream>>>(tet, sdf, cnt, t12, F);
  // 3) bucket offsets
  run_scan(cnt, off, N, bsum, boff, stream);
  // 4) scatter hi values into buckets (destructively bumps off)
  k_scatter<<<FB, TB, 0, stream>>>(tet, sdf, off, inst, F);
  // 5) per-bucket sort + parallel dedupe (wave per bucket, 4 buckets/block)
  k_sortdedupe<<<NB4, TB, 0, stream>>>(off, cnt, inst, uniq, ucnt, N);
  // 6) unique offsets (global lexicographic ranks); uoff[N] = M
  run_scan(ucnt, uoff, N, bsum, boff, stream);
  // 7) compact unique edges + emit verts
  k_verts<<<NB4, TB, 0, stream>>>(off, cnt, uoff, ucnt, inst, uniq, pos, sdf, out, N);
  // 8) combined face-row offsets over [t1 | t2]
  run_scan(t12, C, 2 * F, bsum, boff, stream);
  // 9) emit faces
  k_faces<<<FB, TB, 0, stream>>>(tet, sdf, uoff, ucnt, uniq, C, out, F, N);
}